// Round 12
// baseline (302.460 us; speedup 1.0000x reference)
//
#include <hip/hip_runtime.h>

#define TT 2048
#define NV 1000
#define LOG2E 1.4426950408889634f

// ---- XLA/Eigen rational tanh (R2-lineage), epilogue head only. ----
__device__ __forceinline__ float tanh_fast(float x) {
    const float L = 7.90531110763549805f;
    x = __builtin_amdgcn_fmed3f(x, -L, L);
    float x2 = x * x;
    float p = -2.76076847742355e-16f;
    p = __builtin_fmaf(p, x2, 2.00018790482477e-13f);
    p = __builtin_fmaf(p, x2, -8.60467152213735e-11f);
    p = __builtin_fmaf(p, x2, 5.12229709037114e-08f);
    p = __builtin_fmaf(p, x2, 1.48572235717979e-05f);
    p = __builtin_fmaf(p, x2, 6.37261928875436e-04f);
    p = __builtin_fmaf(p, x2, 4.89352455891786e-03f);
    float q = 1.19825839466702e-06f;
    q = __builtin_fmaf(q, x2, 1.18534705686654e-04f);
    q = __builtin_fmaf(q, x2, 2.26843463243900e-03f);
    q = __builtin_fmaf(q, x2, 4.89352518554385e-03f);
    return (x * p) * __builtin_amdgcn_rcpf(q);
}

// DPP cross-lane; single-use at consumers where possible.
template <int CTRL>
__device__ __forceinline__ float dppf(float x) {
    return __int_as_float(__builtin_amdgcn_update_dpp(
        0, __float_as_int(x), CTRL, 0xF, 0xF, true));
}
#define DPP_XOR1 0xB1   // quad_perm [1,0,3,2]
#define DPP_XOR2 0x4E   // quad_perm [2,3,0,1]
#define DPP_XOR3 0x1B   // quad_perm [3,2,1,0]
#define DPP_ROR4 0x124  // row_ror:4 == xor4 on period-8 data (validated R3-R11)
#define DPP_HMIR 0x141  // row_half_mirror == xor7 within 8-lane half
#define DPP_ROR8 0x128  // row_ror:8 == xor8 within 16-row

// 16 lanes/row (forced by R7/R8 occupancy facts), lane l = s*8+j.
// R12 deltas vs R11 (245 us profiled, absmax 0.0):
//  1. single-rcp gate pair: R = rcp((1+El)(1+Ey)); aL = (nl*a2)*R, sy = a1*R.
//     Error: <=2 ulp relative, non-cancelling — the validated class.
//  2. ul clamp dropped: |pre_g| <= ~16 (weight/emb bounds) -> ul <= 47 << 127;
//     saturation graceful both signs. uc clamp KEPT (c feedback could in
//     principle run away -> exp2->inf->NaN).
//  3. unroll 8 + 2xint4 token ring (halved loop amortization).
// Trans/step: 3 exp + 2 rcp.
extern "C" __global__ void __launch_bounds__(256, 1)
lstm_fused(const int* __restrict__ x, const float* __restrict__ emb,
           const float* __restrict__ W_ih, const float* __restrict__ W_hh,
           const float* __restrict__ b_ih, const float* __restrict__ b_hh,
           const float* __restrict__ W_cls, const float* __restrict__ b_cls,
           float* __restrict__ out)
{
    extern __shared__ float TAB[];  // [1000][16] float2 rows, stride 128 B

    const int tid = threadIdx.x;
    const int l   = tid & 15;
    const int s   = l >> 3;
    const int j   = l & 7;
    const int grp = tid >> 4;

    const int glo = j + (s << 4);          // i_j (s0) or g_j (s1)
    const int ghi = glo + 8;               // f_j (s0) or o_j (s1)
    const float scx = s ? (-2.0f * LOG2E) : -LOG2E;  // lo-slot prescale
    const float scy = -LOG2E;                        // hi-slot sigma prescale
    const float kL  = s ? 1.0f : 0.0f;     // lo numerator: n = 1 - kL*e
    const bool is0 = (s == 0);

    // ---- phase 1: build TAB ----
    {
        float wl[8], wh[8];
        #pragma unroll
        for (int k = 0; k < 8; ++k) {
            wl[k] = W_ih[glo * 8 + k];
            wh[k] = W_ih[ghi * 8 + k];
        }
        const float bl = b_ih[glo] + b_hh[glo];
        const float bh = b_ih[ghi] + b_hh[ghi];
        for (int v = grp; v < NV; v += 16) {
            const float4 e0 = *(const float4*)(emb + v * 8);
            const float4 e1 = *(const float4*)(emb + v * 8 + 4);
            float dl = bl + e0.x*wl[0] + e0.y*wl[1] + e0.z*wl[2] + e0.w*wl[3]
                          + e1.x*wl[4] + e1.y*wl[5] + e1.z*wl[6] + e1.w*wl[7];
            float dh = bh + e0.x*wh[0] + e0.y*wh[1] + e0.z*wh[2] + e0.w*wh[3]
                          + e1.x*wh[4] + e1.y*wh[5] + e1.z*wh[6] + e1.w*wh[7];
            *(float2*)(TAB + v * 32 + l * 2) = make_float2(scx * dl, scy * dh);
        }
    }
    __syncthreads();

    // ---- recurrence ----
    const int b = blockIdx.x * 16 + grp;
    const int* __restrict__ xrow = x + (size_t)b * TT;
    const char* __restrict__ TABl = (const char*)TAB + l * 8;  // lane base

    // xor-ordered W_hh (pairs with m_k = h_{j^m}; validated R3-R11 absmax 0.0)
    float wlo[8], whi[8];
    #pragma unroll
    for (int m = 0; m < 8; ++m) {
        wlo[m] = scx * W_hh[glo * 8 + (j ^ m)];
        whi[m] = scy * W_hh[ghi * 8 + (j ^ m)];
    }

    float c  = 0.0f;
    float hn = 0.0f;   // lane l: h_{l&7} (period-8 within 16-row)

    int4 iA = *(const int4*)(xrow);
    int4 iB = *(const int4*)(xrow + 4);
    float2 xg0 = *(const float2*)(TABl + (iA.x << 7));  // depth-2 prefetch
    float2 xg1 = *(const float2*)(TABl + (iA.y << 7));

    // Dot chain order per component == R6-R11: uA: m0,m2,m4,m6; uB: m1,m3,m5,m7.
#define STEP(XG, NIDX) do {                                                      \
        float mm  = dppf<DPP_HMIR>(hn);          /* m7, multi-use */             \
        float uAl = __builtin_fmaf(wlo[0], hn, XG.x);                            \
        float uAh = __builtin_fmaf(whi[0], hn, XG.y);                            \
        float uBl = dppf<DPP_XOR1>(hn) * wlo[1];                                 \
        float uBh = dppf<DPP_XOR1>(hn) * whi[1];                                 \
        uAl = __builtin_fmaf(dppf<DPP_XOR2>(hn), wlo[2], uAl);                   \
        uAh = __builtin_fmaf(dppf<DPP_XOR2>(hn), whi[2], uAh);                   \
        uBl = __builtin_fmaf(dppf<DPP_XOR3>(hn), wlo[3], uBl);                   \
        uBh = __builtin_fmaf(dppf<DPP_XOR3>(hn), whi[3], uBh);                   \
        uAl = __builtin_fmaf(dppf<DPP_XOR3>(mm), wlo[4], uAl);                   \
        uAh = __builtin_fmaf(dppf<DPP_XOR3>(mm), whi[4], uAh);                   \
        uBl = __builtin_fmaf(dppf<DPP_XOR2>(mm), wlo[5], uBl);                   \
        uBh = __builtin_fmaf(dppf<DPP_XOR2>(mm), whi[5], uBh);                   \
        uAl = __builtin_fmaf(dppf<DPP_XOR1>(mm), wlo[6], uAl);                   \
        uAh = __builtin_fmaf(dppf<DPP_XOR1>(mm), whi[6], uAh);                   \
        uBl = __builtin_fmaf(mm, wlo[7], uBl);                                   \
        uBh = __builtin_fmaf(mm, whi[7], uBh);                                   \
        float ul = uAl + uBl;   /* s0: -log2e*pre_i ; s1: -2log2e*pre_g */       \
        float uh = uAh + uBh;   /* s0/s1: -log2e*pre_{f,o} */                    \
        XG = *(const float2*)(TABl + ((NIDX) << 7));   /* prefetch t+2 */        \
        float el = __builtin_amdgcn_exp2f(ul);         /* no clamp: ul<=~47 */   \
        float ey = __builtin_amdgcn_exp2f(uh);                                   \
        float a1 = 1.0f + el;                                                    \
        float a2 = 1.0f + ey;                                                    \
        float R  = __builtin_amdgcn_rcpf(a1 * a2);     /* shared denominator */  \
        float nl = __builtin_fmaf(-kL, el, 1.0f);      /* s0: 1; s1: 1-el */     \
        float aL = (nl * a2) * R;       /* s0: sig(i);  s1: tanh(g) */           \
        float sy = a1 * R;              /* s0: sig(f);  s1: sig(o)  */           \
        float IG  = dppf<DPP_ROR8>(aL) * aL;      /* sig(i)*tanh(g), both */     \
        float pHi = dppf<DPP_ROR8>(sy);                                          \
        float F   = is0 ? sy : pHi;     /* sig(f) */                             \
        float O   = is0 ? pHi : sy;     /* sig(o) */                             \
        c  = __builtin_fmaf(F, c, IG);                                           \
        float uc = fminf(c * (-2.0f * LOG2E), 126.0f); /* KEEP clamp (NaN) */    \
        float ec = __builtin_amdgcn_exp2f(uc);                                   \
        float tc = (1.0f - ec) * __builtin_amdgcn_rcpf(1.0f + ec);               \
        hn = O * tc;                                                             \
    } while (0)

    for (int t = 0; t < TT; t += 8) {
        const int nb = (t + 8 < TT) ? (t + 8) : 0;     // clamp tail prefetch
        int4 iN1 = *(const int4*)(xrow + nb);
        int4 iN2 = *(const int4*)(xrow + nb + 4);
        STEP(xg0, iA.z);
        STEP(xg1, iA.w);
        STEP(xg0, iB.x);
        STEP(xg1, iB.y);
        STEP(xg0, iB.z);
        STEP(xg1, iB.w);
        STEP(xg0, iN1.x);
        STEP(xg1, iN1.y);
        iA = iN1; iB = iN2;
    }
#undef STEP

    // ---- head: out[b] = 0.5 + 0.5*tanh(0.5*(h.W_cls + b_cls)) ----
    // Lane l==0: hn=h_0, v_m=h_m -> same summation order as R2-R11.
    {
        float v1 = dppf<DPP_XOR1>(hn);
        float v2 = dppf<DPP_XOR2>(hn);
        float v3 = dppf<DPP_XOR3>(hn);
        float v4 = dppf<DPP_ROR4>(hn);
        float v5 = dppf<DPP_XOR1>(v4);
        float v6 = dppf<DPP_XOR2>(v4);
        float v7 = dppf<DPP_XOR3>(v4);
        if (l == 0) {
            float z = b_cls[0]
                + hn * W_cls[0] + v1 * W_cls[1] + v2 * W_cls[2] + v3 * W_cls[3]
                + v4 * W_cls[4] + v5 * W_cls[5] + v6 * W_cls[6] + v7 * W_cls[7];
            out[b] = __builtin_fmaf(0.5f, tanh_fast(0.5f * z), 0.5f);
        }
    }
}

extern "C" void kernel_launch(void* const* d_in, const int* in_sizes, int n_in,
                              void* d_out, int out_size, void* d_ws, size_t ws_size,
                              hipStream_t stream)
{
    (void)in_sizes; (void)n_in; (void)d_ws; (void)ws_size; (void)out_size;
    const int*   x     = (const int*)  d_in[0];
    const float* emb   = (const float*)d_in[1];
    const float* W_ih  = (const float*)d_in[2];
    const float* W_hh  = (const float*)d_in[3];
    const float* b_ih  = (const float*)d_in[4];
    const float* b_hh  = (const float*)d_in[5];
    const float* W_cls = (const float*)d_in[6];
    const float* b_cls = (const float*)d_in[7];
    float* out = (float*)d_out;

    const int lds_bytes = NV * 16 * 8;  // 128000 <= 163840 (gfx950 opt-in)
    hipFuncSetAttribute((const void*)lstm_fused,
                        hipFuncAttributeMaxDynamicSharedMemorySize, lds_bytes);

    lstm_fused<<<dim3(256), dim3(256), lds_bytes, stream>>>(
        x, emb, W_ih, W_hh, b_ih, b_hh, W_cls, b_cls, out);
}

// Round 13
// 299.055 us; speedup vs baseline: 1.0114x; 1.0114x over previous
//
#include <hip/hip_runtime.h>

#define TT 2048
#define NV 1000
#define LOG2E 1.4426950408889634f

// ---- XLA/Eigen rational tanh (R2-lineage), epilogue head only. ----
__device__ __forceinline__ float tanh_fast(float x) {
    const float L = 7.90531110763549805f;
    x = __builtin_amdgcn_fmed3f(x, -L, L);
    float x2 = x * x;
    float p = -2.76076847742355e-16f;
    p = __builtin_fmaf(p, x2, 2.00018790482477e-13f);
    p = __builtin_fmaf(p, x2, -8.60467152213735e-11f);
    p = __builtin_fmaf(p, x2, 5.12229709037114e-08f);
    p = __builtin_fmaf(p, x2, 1.48572235717979e-05f);
    p = __builtin_fmaf(p, x2, 6.37261928875436e-04f);
    p = __builtin_fmaf(p, x2, 4.89352455891786e-03f);
    float q = 1.19825839466702e-06f;
    q = __builtin_fmaf(q, x2, 1.18534705686654e-04f);
    q = __builtin_fmaf(q, x2, 2.26843463243900e-03f);
    q = __builtin_fmaf(q, x2, 4.89352518554385e-03f);
    return (x * p) * __builtin_amdgcn_rcpf(q);
}

// DPP cross-lane; single-use at consumers where possible.
template <int CTRL>
__device__ __forceinline__ float dppf(float x) {
    return __int_as_float(__builtin_amdgcn_update_dpp(
        0, __float_as_int(x), CTRL, 0xF, 0xF, true));
}
#define DPP_XOR1 0xB1   // quad_perm [1,0,3,2]
#define DPP_XOR2 0x4E   // quad_perm [2,3,0,1]
#define DPP_XOR3 0x1B   // quad_perm [3,2,1,0]
#define DPP_ROR4 0x124  // row_ror:4 == xor4 on period-8 data (validated R3-R12)
#define DPP_HMIR 0x141  // row_half_mirror == xor7 within 8-lane half
#define DPP_ROR8 0x128  // row_ror:8 == xor8 within 16-row

// 16 lanes/row (forced by R7/R8 occupancy facts), lane l = s*8+j.
// R13 = best-of merge:
//  - R11's PARALLEL two-rcp activation chains (R12's shared-rcp serialized
//    them: busy -9 but stall +18 -> net loss. Reverted.)
//  - R12's ul-clamp drop + unroll-8 (validated absmax 0.0).
//  - NEW: c kept in pre-scaled form c' = -2log2e*c by folding the constant
//    into the s0-lane numerator (nlB): aL(s0) = K*sig(i), so IG = K*i*g on
//    both lanes (commutative ROR8 product). Deletes the uc mul, -4 cy chain.
// Trans/step: 3 exp + 3 rcp (parallel pairs).
extern "C" __global__ void __launch_bounds__(256, 1)
lstm_fused(const int* __restrict__ x, const float* __restrict__ emb,
           const float* __restrict__ W_ih, const float* __restrict__ W_hh,
           const float* __restrict__ b_ih, const float* __restrict__ b_hh,
           const float* __restrict__ W_cls, const float* __restrict__ b_cls,
           float* __restrict__ out)
{
    extern __shared__ float TAB[];  // [1000][16] float2 rows, stride 128 B

    const int tid = threadIdx.x;
    const int l   = tid & 15;
    const int s   = l >> 3;
    const int j   = l & 7;
    const int grp = tid >> 4;

    const int glo = j + (s << 4);          // i_j (s0) or g_j (s1)
    const int ghi = glo + 8;               // f_j (s0) or o_j (s1)
    const float scx = s ? (-2.0f * LOG2E) : -LOG2E;  // lo-slot prescale
    const float scy = -LOG2E;                        // hi-slot sigma prescale
    const float kL  = s ? 1.0f : 0.0f;               // lo numerator e-coeff
    const float nlB = s ? 1.0f : (-2.0f * LOG2E);    // lo numerator base (K-fold)
    const bool is0 = (s == 0);

    // ---- phase 1: build TAB ----
    {
        float wl[8], wh[8];
        #pragma unroll
        for (int k = 0; k < 8; ++k) {
            wl[k] = W_ih[glo * 8 + k];
            wh[k] = W_ih[ghi * 8 + k];
        }
        const float bl = b_ih[glo] + b_hh[glo];
        const float bh = b_ih[ghi] + b_hh[ghi];
        for (int v = grp; v < NV; v += 16) {
            const float4 e0 = *(const float4*)(emb + v * 8);
            const float4 e1 = *(const float4*)(emb + v * 8 + 4);
            float dl = bl + e0.x*wl[0] + e0.y*wl[1] + e0.z*wl[2] + e0.w*wl[3]
                          + e1.x*wl[4] + e1.y*wl[5] + e1.z*wl[6] + e1.w*wl[7];
            float dh = bh + e0.x*wh[0] + e0.y*wh[1] + e0.z*wh[2] + e0.w*wh[3]
                          + e1.x*wh[4] + e1.y*wh[5] + e1.z*wh[6] + e1.w*wh[7];
            *(float2*)(TAB + v * 32 + l * 2) = make_float2(scx * dl, scy * dh);
        }
    }
    __syncthreads();

    // ---- recurrence ----
    const int b = blockIdx.x * 16 + grp;
    const int* __restrict__ xrow = x + (size_t)b * TT;
    const char* __restrict__ TABl = (const char*)TAB + l * 8;  // lane base

    // xor-ordered W_hh (pairs with m_k = h_{j^m}; validated R3-R12 absmax 0.0)
    float wlo[8], whi[8];
    #pragma unroll
    for (int m = 0; m < 8; ++m) {
        wlo[m] = scx * W_hh[glo * 8 + (j ^ m)];
        whi[m] = scy * W_hh[ghi * 8 + (j ^ m)];
    }

    float c  = 0.0f;   // pre-scaled cell: c' = -2log2e * c_true
    float hn = 0.0f;   // lane l: h_{l&7} (period-8 within 16-row)

    int4 iA = *(const int4*)(xrow);
    int4 iB = *(const int4*)(xrow + 4);
    float2 xg0 = *(const float2*)(TABl + (iA.x << 7));  // depth-2 prefetch
    float2 xg1 = *(const float2*)(TABl + (iA.y << 7));

    // Dot chain order per component == R6-R12: uA: m0,m2,m4,m6; uB: m1,m3,m5,m7.
#define STEP(XG, NIDX) do {                                                      \
        float mm  = dppf<DPP_HMIR>(hn);          /* m7, multi-use */             \
        float uAl = __builtin_fmaf(wlo[0], hn, XG.x);                            \
        float uAh = __builtin_fmaf(whi[0], hn, XG.y);                            \
        float uBl = dppf<DPP_XOR1>(hn) * wlo[1];                                 \
        float uBh = dppf<DPP_XOR1>(hn) * whi[1];                                 \
        uAl = __builtin_fmaf(dppf<DPP_XOR2>(hn), wlo[2], uAl);                   \
        uAh = __builtin_fmaf(dppf<DPP_XOR2>(hn), whi[2], uAh);                   \
        uBl = __builtin_fmaf(dppf<DPP_XOR3>(hn), wlo[3], uBl);                   \
        uBh = __builtin_fmaf(dppf<DPP_XOR3>(hn), whi[3], uBh);                   \
        uAl = __builtin_fmaf(dppf<DPP_XOR3>(mm), wlo[4], uAl);                   \
        uAh = __builtin_fmaf(dppf<DPP_XOR3>(mm), whi[4], uAh);                   \
        uBl = __builtin_fmaf(dppf<DPP_XOR2>(mm), wlo[5], uBl);                   \
        uBh = __builtin_fmaf(dppf<DPP_XOR2>(mm), whi[5], uBh);                   \
        uAl = __builtin_fmaf(dppf<DPP_XOR1>(mm), wlo[6], uAl);                   \
        uAh = __builtin_fmaf(dppf<DPP_XOR1>(mm), whi[6], uAh);                   \
        uBl = __builtin_fmaf(mm, wlo[7], uBl);                                   \
        uBh = __builtin_fmaf(mm, whi[7], uBh);                                   \
        float uh = uAh + uBh;   /* s0/s1: -log2e*pre_{f,o}  (sy chain first) */  \
        float ul = uAl + uBl;   /* s0: -log2e*pre_i ; s1: -2log2e*pre_g */       \
        XG = *(const float2*)(TABl + ((NIDX) << 7));   /* prefetch t+2 */        \
        float ey = __builtin_amdgcn_exp2f(uh);                                   \
        float el = __builtin_amdgcn_exp2f(ul);         /* no clamp: bounded */   \
        float sy = __builtin_amdgcn_rcpf(1.0f + ey);   /* sig(f) or sig(o) */    \
        float nl = __builtin_fmaf(-kL, el, nlB);       /* s0: K; s1: 1-el */     \
        float aL = nl * __builtin_amdgcn_rcpf(1.0f + el); /* K*sig(i)/tanh(g) */ \
        float pHi = dppf<DPP_ROR8>(sy);                                          \
        float F   = is0 ? sy : pHi;     /* sig(f) */                             \
        float O   = is0 ? pHi : sy;     /* sig(o) */                             \
        float IG  = dppf<DPP_ROR8>(aL) * aL;   /* K*sig(i)*tanh(g), both */      \
        c  = __builtin_fmaf(F, c, IG);         /* pre-scaled cell update */      \
        float ec = __builtin_amdgcn_exp2f(fminf(c, 126.0f)); /* KEEP clamp */    \
        float tc = (1.0f - ec) * __builtin_amdgcn_rcpf(1.0f + ec);               \
        hn = O * tc;                                                             \
    } while (0)

    for (int t = 0; t < TT; t += 8) {
        const int nb = (t + 8 < TT) ? (t + 8) : 0;     // clamp tail prefetch
        int4 iN1 = *(const int4*)(xrow + nb);
        int4 iN2 = *(const int4*)(xrow + nb + 4);
        STEP(xg0, iA.z);
        STEP(xg1, iA.w);
        STEP(xg0, iB.x);
        STEP(xg1, iB.y);
        STEP(xg0, iB.z);
        STEP(xg1, iB.w);
        STEP(xg0, iN1.x);
        STEP(xg1, iN1.y);
        iA = iN1; iB = iN2;
    }
#undef STEP

    // ---- head: out[b] = 0.5 + 0.5*tanh(0.5*(h.W_cls + b_cls)) ----
    // Lane l==0: hn=h_0, v_m=h_m -> same summation order as R2-R12.
    {
        float v1 = dppf<DPP_XOR1>(hn);
        float v2 = dppf<DPP_XOR2>(hn);
        float v3 = dppf<DPP_XOR3>(hn);
        float v4 = dppf<DPP_ROR4>(hn);
        float v5 = dppf<DPP_XOR1>(v4);
        float v6 = dppf<DPP_XOR2>(v4);
        float v7 = dppf<DPP_XOR3>(v4);
        if (l == 0) {
            float z = b_cls[0]
                + hn * W_cls[0] + v1 * W_cls[1] + v2 * W_cls[2] + v3 * W_cls[3]
                + v4 * W_cls[4] + v5 * W_cls[5] + v6 * W_cls[6] + v7 * W_cls[7];
            out[b] = __builtin_fmaf(0.5f, tanh_fast(0.5f * z), 0.5f);
        }
    }
}

extern "C" void kernel_launch(void* const* d_in, const int* in_sizes, int n_in,
                              void* d_out, int out_size, void* d_ws, size_t ws_size,
                              hipStream_t stream)
{
    (void)in_sizes; (void)n_in; (void)d_ws; (void)ws_size; (void)out_size;
    const int*   x     = (const int*)  d_in[0];
    const float* emb   = (const float*)d_in[1];
    const float* W_ih  = (const float*)d_in[2];
    const float* W_hh  = (const float*)d_in[3];
    const float* b_ih  = (const float*)d_in[4];
    const float* b_hh  = (const float*)d_in[5];
    const float* W_cls = (const float*)d_in[6];
    const float* b_cls = (const float*)d_in[7];
    float* out = (float*)d_out;

    const int lds_bytes = NV * 16 * 8;  // 128000 <= 163840 (gfx950 opt-in)
    hipFuncSetAttribute((const void*)lstm_fused,
                        hipFuncAttributeMaxDynamicSharedMemorySize, lds_bytes);

    lstm_fused<<<dim3(256), dim3(256), lds_bytes, stream>>>(
        x, emb, W_ih, W_hh, b_ih, b_hh, W_cls, b_cls, out);
}